// Round 6
// baseline (49.154 us; speedup 1.0000x reference)
//
#include <hip/hip_runtime.h>

// Depthwise conv1d along L, K=25, replicate padding, + scalar bias.
// x: [B=32, L=2048, C=512] f32 -> out same shape.
//
// R5: 2-phase pipeline with counted vmcnt (T3-lite). Each block owns a
// 256-output L-chunk x 128 channels. LDS = 128-row ring (64KB) of 512B row
// segments. Per step t (32 outputs): prefetch page t+3 (32 rows, 16KB) via
// global_load_lds, s_waitcnt vmcnt(4) (page t+2 complete, t+3 in flight),
// raw s_barrier, compute from ring. No __syncthreads -> no vmcnt(0) drain
// in the main loop; halo rows reused in LDS across steps (no refetch).
// NT stores kept (R2/R3 A/B: -48MB FETCH).

typedef float f32x4 __attribute__((ext_vector_type(4)));

constexpr int K      = 25;
constexpr int HALF   = 12;
constexpr int BB     = 32;
constexpr int LL     = 2048;
constexpr int CC     = 512;
constexpr int QC     = 128;              // channels per block
constexpr int STEP   = 32;               // outputs per step
constexpr int NSTEP  = 8;                // steps per block
constexpr int LCHUNK = STEP * NSTEP;     // 256
constexpr int NLCH   = LL / LCHUNK;      // 8
constexpr int NQ     = CC / QC;          // 4
constexpr int NBLK   = BB * NQ * NLCH;   // 1024
constexpr int RING   = 128;              // ring rows; 128 * 128 floats = 64 KB
// virtual row v = (l - Lbase) + 32; page p holds v in [32p, 32p+32), p = 0..9.
// step t computes l in [Lbase+32t, +32): needs v in [32t+20, 32t+76) = pages t..t+2.

__device__ inline void gll16(const float* g, float* l) {
    __builtin_amdgcn_global_load_lds(
        (const __attribute__((address_space(1))) void*)g,
        (__attribute__((address_space(3))) void*)l, 16, 0, 0);
}

__global__ __launch_bounds__(256) void conv1d_dw_kernel(
    const float* __restrict__ x,
    const float* __restrict__ w,
    const float* __restrict__ bias_p,
    float* __restrict__ out)
{
    __shared__ float lds[RING * QC];

    // XCD-aware swizzle: contiguous logical-block runs per XCD.
    const int bid  = blockIdx.x;
    const int lbid = (bid & 7) * (NBLK >> 3) + (bid >> 3);

    const int lch = lbid & (NLCH - 1);        // adjacent lbid = adjacent L-chunk
    const int q   = (lbid >> 3) & (NQ - 1);
    const int b   = lbid >> 5;

    const int tid  = threadIdx.x;
    const int wv   = tid >> 6;                // 0..3
    const int lane = tid & 63;
    const int lgrp = tid >> 5;                // 0..7 (4 outputs each)
    const int c4   = tid & 31;                // f32x4 column

    const int Lbase = lch * LCHUNK;
    const float* xq = x   + (size_t)b * LL * CC + q * QC;
    float*       oq = out + (size_t)b * LL * CC + q * QC;

    float wr[K];
#pragma unroll
    for (int k = 0; k < K; ++k) wr[k] = w[k];   // wave-uniform -> SGPR
    const float bias = bias_p[0];

    // stage page p: 32 rows (v = 32p+s) of 512B; 4 gll16/thread (2 rows/gll).
    // LDS dest is wave-uniform base + lane*16 (linear, matches HW semantics).
    auto stage = [&](int p) {
#pragma unroll
        for (int i = 0; i < 4; ++i) {
            const int sbase = 8 * wv + 2 * i;                 // wave-uniform
            const int v0    = 32 * p + sbase;                 // even -> pair never wraps ring
            const int s     = sbase + (lane >> 5);            // per-lane row within pair
            const int li    = max(0, min(LL - 1, Lbase + 32 * p + s - 32));
            gll16(xq + (size_t)li * CC + (lane & 31) * 4,
                  lds + (size_t)(v0 & (RING - 1)) * QC);
        }
    };

    stage(0); stage(1); stage(2);   // 12 gll outstanding, no wait yet

#pragma unroll
    for (int t = 0; t < NSTEP; ++t) {
        // all waves done reading page t-1 before its ring slots are overwritten
        __builtin_amdgcn_s_barrier();
        if (t < NSTEP - 1) {
            stage(t + 3);
            asm volatile("s_waitcnt vmcnt(4)" ::: "memory");  // pages <= t+2 landed
        } else {
            asm volatile("s_waitcnt vmcnt(0)" ::: "memory");
        }
        __builtin_amdgcn_s_barrier();

        f32x4 acc[4];
#pragma unroll
        for (int jj = 0; jj < 4; ++jj) acc[jj] = (f32x4){bias, bias, bias, bias};

        // outputs l = Lbase + 32t + lgrp*4 + jj ; input v = 32t + lgrp*4 + 20 + rr
        const int vb = 32 * t + lgrp * 4 + 20;
#pragma unroll
        for (int rr = 0; rr < 28; ++rr) {
            const int v = vb + rr;
            const f32x4 rv = *reinterpret_cast<const f32x4*>(
                lds + (size_t)(v & (RING - 1)) * QC + c4 * 4);
#pragma unroll
            for (int jj = 0; jj < 4; ++jj) {
                const int k = rr - jj;                 // compile-time per (rr,jj)
                if (k >= 0 && k < K) acc[jj] += wr[k] * rv;
            }
        }

        const int l0 = Lbase + 32 * t + lgrp * 4;
#pragma unroll
        for (int jj = 0; jj < 4; ++jj)
            __builtin_nontemporal_store(acc[jj],
                reinterpret_cast<f32x4*>(oq + (size_t)(l0 + jj) * CC) + c4);
    }
}

extern "C" void kernel_launch(void* const* d_in, const int* in_sizes, int n_in,
                              void* d_out, int out_size, void* d_ws, size_t ws_size,
                              hipStream_t stream) {
    const float* x  = (const float*)d_in[0];
    const float* w  = (const float*)d_in[1];
    const float* bp = (const float*)d_in[2];
    float* out      = (float*)d_out;

    conv1d_dw_kernel<<<NBLK, 256, 0, stream>>>(x, w, bp, out);
}

// Round 7
// 43.581 us; speedup vs baseline: 1.1279x; 1.1279x over previous
//
#include <hip/hip_runtime.h>

// Depthwise conv1d along L, K=25, replicate padding, + scalar bias.
// x: [B=32, L=2048, C=512] f32 -> out same shape.
//
// R6: cut staging traffic + deepen inter-block overlap (R5's intra-block
// pipeline was null). R4 skeleton (stage-all -> sync -> compute -> NT store)
// with TL=128 outputs x 64 channels per block: halo ratio 152/128 = 1.19x
// (was 1.75x), LDS 38 KB -> 4 blocks/CU co-resident (was 2).

typedef float f32x4 __attribute__((ext_vector_type(4)));

constexpr int K     = 25;
constexpr int HALF  = 12;
constexpr int BB    = 32;
constexpr int LL    = 2048;
constexpr int CC    = 512;
constexpr int QCH   = 64;               // channels per block
constexpr int QC4   = QCH / 4;          // 16 f32x4 per row segment
constexpr int TL    = 128;              // L-outputs per block
constexpr int NROWS = TL + K - 1;       // 152 staged rows
constexpr int NQUAD = NROWS / 4;        // 38 gll-quads (1KB each)
constexpr int NQ    = CC / QCH;         // 8
constexpr int NT    = LL / TL;          // 16
constexpr int NBLK  = BB * NQ * NT;     // 4096

__device__ inline void gll16(const float* g, float* l) {
    __builtin_amdgcn_global_load_lds(
        (const __attribute__((address_space(1))) void*)g,
        (__attribute__((address_space(3))) void*)l, 16, 0, 0);
}

__global__ __launch_bounds__(256) void conv1d_dw_kernel(
    const float* __restrict__ x,
    const float* __restrict__ w,
    const float* __restrict__ bias_p,
    float* __restrict__ out)
{
    __shared__ float lds[NROWS * QCH];      // 38912 B

    // XCD-aware swizzle; adjacent lbid = adjacent L-tile of same (b,qc)
    // so halo lines are L2-warm on the same XCD.
    const int bid  = blockIdx.x;
    const int lbid = (bid & 7) * (NBLK >> 3) + (bid >> 3);

    const int lt = lbid & (NT - 1);          // 0..15  L-tile
    const int qc = (lbid >> 4) & (NQ - 1);   // 0..7   channel slice
    const int b  = lbid >> 7;                // 0..31

    const int tid  = threadIdx.x;
    const int wv   = tid >> 6;               // 0..3
    const int lane = tid & 63;

    const int Lbase = lt * TL;
    const float* xq = x   + (size_t)b * LL * CC + qc * QCH;
    float*       oq = out + (size_t)b * LL * CC + qc * QCH;

    // ---- stage 152 rows x 256 B (38 x 1KB gll16 per block) ----
#pragma unroll
    for (int i = 0; i < 10; ++i) {
        const int qd = wv + 4 * i;                    // wave-uniform
        if (qd < NQUAD) {
            const int v  = qd * 4 + (lane >> 4);      // staged row 0..151
            const int li = max(0, min(LL - 1, Lbase + v - HALF));
            gll16(xq + (size_t)li * CC + (lane & 15) * 4,
                  lds + (size_t)qd * 4 * QCH);        // linear dest, +lane*16
        }
    }

    float wr[K];
#pragma unroll
    for (int k = 0; k < K; ++k) wr[k] = w[k];         // wave-uniform -> SGPR
    const float bias = bias_p[0];

    __syncthreads();                                  // vmcnt(0) drain here

    // ---- compute: thread = (lgrp = tid>>4 -> 8 l-outputs, c4 = tid&15) ----
    const int lgrp = tid >> 4;               // 0..15
    const int c4   = tid & 15;               // f32x4 column

    f32x4 acc[8];
#pragma unroll
    for (int j = 0; j < 8; ++j) acc[j] = (f32x4){bias, bias, bias, bias};

    const f32x4* ldsv = reinterpret_cast<const f32x4*>(lds);
#pragma unroll
    for (int rr = 0; rr < 32; ++rr) {
        const f32x4 rv = ldsv[(size_t)(lgrp * 8 + rr) * QC4 + c4];
#pragma unroll
        for (int j = 0; j < 8; ++j) {
            const int k = rr - j;            // compile-time per (rr,j)
            if (k >= 0 && k < K) acc[j] += wr[k] * rv;
        }
    }

    const int l0 = Lbase + lgrp * 8;
#pragma unroll
    for (int j = 0; j < 8; ++j)
        __builtin_nontemporal_store(acc[j],
            reinterpret_cast<f32x4*>(oq + (size_t)(l0 + j) * CC) + c4);
}

extern "C" void kernel_launch(void* const* d_in, const int* in_sizes, int n_in,
                              void* d_out, int out_size, void* d_ws, size_t ws_size,
                              hipStream_t stream) {
    const float* x  = (const float*)d_in[0];
    const float* w  = (const float*)d_in[1];
    const float* bp = (const float*)d_in[2];
    float* out      = (float*)d_out;

    conv1d_dw_kernel<<<NBLK, 256, 0, stream>>>(x, w, bp, out);
}